// Round 1
// baseline (3847.550 us; speedup 1.0000x reference)
//
#include <hip/hip_runtime.h>
#include <hip/hip_bf16.h>
#include <math.h>

#define EPS 1e-6f

namespace {

constexpr int Bb = 4, Ss = 512, Dd = 512, Ii = 1024, Cc = 64;
constexpr int nCk = Ss / Cc;           // 8 chunks
constexpr int RowsC = Bb * Cc;         // 256
constexpr int RowsAll = Bb * Ss;       // 2048

__device__ __forceinline__ float sigmoidf_(float x) { return 1.f / (1.f + expf(-x)); }
__device__ __forceinline__ float siluf_(float x)    { return x / (1.f + expf(-x)); }

__device__ __forceinline__ float block_reduce_sum(float v, float* red) {
  int tid = threadIdx.x;
  red[tid] = v; __syncthreads();
  for (int s = 128; s > 0; s >>= 1) {
    if (tid < s) red[tid] += red[tid + s];
    __syncthreads();
  }
  float r = red[0]; __syncthreads();
  return r;
}

// Generic strided GEMM: C[m,n] = act( sum_k A[m*sma+k*ska] * (kw?kw[k]:1) * B[k*skb+n*snb] )
// Tile 64x64, BK=16, 256 threads, 4x4 per thread. All dims: M%64==0, N%64==0, K%16==0.
template<int ACT>   // 0 = none, 1 = silu
__global__ __launch_bounds__(256) void gemm_k(
    const float* __restrict__ A, const float* __restrict__ B, float* __restrict__ C,
    int M, int N, int K,
    int sma, int ska, int skb, int snb, int ldc,
    const float* __restrict__ kw)
{
  constexpr int BM = 64, BN = 64, BK = 16;
  __shared__ float As[BK][BM + 1];
  __shared__ float Bs[BK][BN + 1];
  const int tid = threadIdx.x;
  const int tx = tid & 15, ty = tid >> 4;
  const int bm = blockIdx.y * BM, bn = blockIdx.x * BN;

  float acc[4][4] = {};

  for (int k0 = 0; k0 < K; k0 += BK) {
    // ---- load A tile (64x16), pick mapping so unit-stride index is tid-fast
    if (ska == 1) {           // A row-major: kk fast
      #pragma unroll
      for (int i = 0; i < 4; ++i) {
        int e = tid + i * 256;
        int kk = e & 15, m = e >> 4;
        float a = A[(size_t)(bm + m) * sma + (size_t)(k0 + kk)];
        if (kw) a *= kw[k0 + kk];
        As[kk][m] = a;
      }
    } else {                  // A transposed (sma==1): m fast
      #pragma unroll
      for (int i = 0; i < 4; ++i) {
        int e = tid + i * 256;
        int m = e & 63, kk = e >> 6;
        float a = A[(size_t)(bm + m) + (size_t)(k0 + kk) * ska];
        if (kw) a *= kw[k0 + kk];
        As[kk][m] = a;
      }
    }
    // ---- load B tile (16x64)
    if (snb == 1) {           // B row-major in n: n fast
      #pragma unroll
      for (int i = 0; i < 4; ++i) {
        int e = tid + i * 256;
        int n = e & 63, kk = e >> 6;
        Bs[kk][n] = B[(size_t)(k0 + kk) * skb + (size_t)(bn + n)];
      }
    } else {                  // skb==1: kk fast
      #pragma unroll
      for (int i = 0; i < 4; ++i) {
        int e = tid + i * 256;
        int kk = e & 15, n = e >> 4;
        Bs[kk][n] = B[(size_t)(k0 + kk) + (size_t)(bn + n) * snb];
      }
    }
    __syncthreads();

    #pragma unroll
    for (int kk = 0; kk < BK; ++kk) {
      float av[4], bv[4];
      #pragma unroll
      for (int i = 0; i < 4; ++i) av[i] = As[kk][ty * 4 + i];
      #pragma unroll
      for (int j = 0; j < 4; ++j) bv[j] = Bs[kk][tx * 4 + j];
      #pragma unroll
      for (int i = 0; i < 4; ++i)
        #pragma unroll
        for (int j = 0; j < 4; ++j)
          acc[i][j] += av[i] * bv[j];
    }
    __syncthreads();
  }

  #pragma unroll
  for (int i = 0; i < 4; ++i)
    #pragma unroll
    for (int j = 0; j < 4; ++j) {
      float v = acc[i][j];
      if (ACT == 1) v = v / (1.f + expf(-v));
      C[(size_t)(bm + ty * 4 + i) * ldc + (bn + tx * 4 + j)] = v;
    }
}

// gather chunk ci of x into contiguous [256, D] rows (b*64+t)
__global__ __launch_bounds__(256) void gather_k(const float* __restrict__ x,
                                                float* __restrict__ xc, int ci) {
  int row = blockIdx.x;            // b*64+t
  int b = row >> 6, t = row & 63;
  const float* src = x + ((size_t)b * Ss + (size_t)ci * Cc + t) * Dd;
  float* dst = xc + (size_t)row * Dd;
  for (int d = threadIdx.x; d < Dd; d += 256) dst[d] = src[d];
}

// per-token gates: al/th/et  (one block per token)
__global__ __launch_bounds__(256) void gates_k(
    const float* __restrict__ xc,
    const float* __restrict__ aw, const float* __restrict__ ab,
    const float* __restrict__ tw, const float* __restrict__ tb,
    const float* __restrict__ ew, const float* __restrict__ eb,
    float* __restrict__ al, float* __restrict__ th, float* __restrict__ et)
{
  __shared__ float red[256];
  int t = blockIdx.x, tid = threadIdx.x;
  float sa = 0.f, st = 0.f, se = 0.f;
  for (int b = 0; b < Bb; ++b) {
    const float* xr = xc + (size_t)(b * Cc + t) * Dd;
    for (int d = tid; d < Dd; d += 256) {
      float xv = xr[d];
      sa += xv * aw[d]; st += xv * tw[d]; se += xv * ew[d];
    }
  }
  sa = block_reduce_sum(sa, red);
  st = block_reduce_sum(st, red);
  se = block_reduce_sum(se, red);
  if (tid == 0) {
    al[t] = sigmoidf_(sa + Bb * ab[0]);
    th[t] = sigmoidf_(st + Bb * tb[0]) * 0.01f;
    et[t] = sigmoidf_(se + Bb * eb[0]);
  }
}

// sequential length-64 scans for the update weights (trivial cost)
__global__ void gate_scan_k(const float* __restrict__ al, const float* __restrict__ et,
                            float* __restrict__ wB, float* __restrict__ wE,
                            float* __restrict__ scal)
{
  if (threadIdx.x != 0 || blockIdx.x != 0) return;
  float beta[Cc], wb[Cc], ce[Cc], E[Cc], T[Cc];
  for (int i = 0; i < Cc; ++i) beta[i] = 1.f - al[i];
  wb[Cc - 1] = 1.f;
  for (int m = Cc - 2; m >= 0; --m) wb[m] = wb[m + 1] * beta[m + 1];
  float bc_last = wb[0] * beta[0];
  float p = 1.f, A = 0.f;
  for (int m = 0; m < Cc; ++m) { p *= et[m]; ce[m] = p; A += wb[m] * ce[m]; }
  E[Cc - 1] = 1.f; T[Cc - 1] = 1.f;
  for (int n = Cc - 2; n >= 0; --n) {
    E[n] = E[n + 1] * et[n + 1];
    T[n] = wb[n] + et[n + 1] * T[n + 1];
  }
  for (int b = 0; b < Bb; ++b)
    for (int t = 0; t < Cc; ++t) { wB[b * Cc + t] = T[t]; wE[b * Cc + t] = E[t]; }
  scal[0] = bc_last; scal[1] = A; scal[2] = ce[Cc - 1];
}

// out = rms(silu(in)) * nw   (one block per row, D=512)
__global__ __launch_bounds__(256) void silu_rms_k(const float* __restrict__ in,
                                                  float* __restrict__ out,
                                                  const float* __restrict__ nw)
{
  __shared__ float red[256];
  int row = blockIdx.x, tid = threadIdx.x;
  const float* ir = in + (size_t)row * Dd;
  float s0 = siluf_(ir[tid]), s1 = siluf_(ir[tid + 256]);
  float ss = block_reduce_sum(s0 * s0 + s1 * s1, red);
  float r = rsqrtf(ss / (float)Dd + EPS);
  out[(size_t)row * Dd + tid]       = s0 * r * nw[tid];
  out[(size_t)row * Dd + tid + 256] = s1 * r * nw[tid + 256];
}

__global__ void silu_k(const float* __restrict__ in, float* __restrict__ out, int n) {
  int i = blockIdx.x * blockDim.x + threadIdx.x;
  if (i < n) out[i] = siluf_(in[i]);
}

// per-row loss backward: produce dY and gyr (= g*y*r, for ln-grad)
__global__ __launch_bounds__(256) void loss_back_k(
    const float* __restrict__ Kr, const float* __restrict__ Vr,
    const float* __restrict__ Y, const float* __restrict__ ln,
    const float* __restrict__ th,
    float* __restrict__ dY, float* __restrict__ gyr)
{
  __shared__ float red[256];
  int row = blockIdx.x, tid = threadIdx.x;
  int t = row & 63;
  size_t base = (size_t)row * Dd;
  float y0 = Y[base + tid], y1 = Y[base + tid + 256];
  float ss = block_reduce_sum(y0 * y0 + y1 * y1, red);
  float r = rsqrtf(ss / (float)Dd + EPS);
  float c = 2.f * th[t] / (float)Dd;
  float ln0 = ln[tid], ln1 = ln[tid + 256];
  float x0 = Kr[base + tid], x1 = Kr[base + tid + 256];
  float t0 = Vr[base + tid], t1 = Vr[base + tid + 256];
  float g0 = c * ((x0 + y0 * r * ln0) - t0);
  float g1 = c * ((x1 + y1 * r * ln1) - t1);
  float s = block_reduce_sum(g0 * ln0 * y0 + g1 * ln1 * y1, red);
  float coef = r * r * r * s / (float)Dd;
  dY[base + tid]        = r * g0 * ln0 - coef * y0;
  dY[base + tid + 256]  = r * g1 * ln1 - coef * y1;
  gyr[base + tid]       = g0 * y0 * r;
  gyr[base + tid + 256] = g1 * y1 * r;
}

// dH *= silu'(Z0)
__global__ void dz_k(float* __restrict__ dH, const float* __restrict__ Z0, int n) {
  int i = blockIdx.x * blockDim.x + threadIdx.x;
  if (i < n) {
    float z = Z0[i], s = 1.f / (1.f + expf(-z));
    dH[i] *= s * (1.f + z * (1.f - s));
  }
}

// Gln[d] = sum_r w[r]*gyr[r,d]  (both weightings)
__global__ void colsum_k(const float* __restrict__ gyr,
                         const float* __restrict__ wB, const float* __restrict__ wE,
                         float* __restrict__ GlnM, float* __restrict__ GlnS) {
  int d = blockIdx.x * blockDim.x + threadIdx.x;
  if (d < Dd) {
    float sm = 0.f, se = 0.f;
    for (int r = 0; r < RowsC; ++r) {
      float v = gyr[(size_t)r * Dd + d];
      sm += wB[r] * v; se += wE[r] * v;
    }
    GlnM[d] = sm; GlnS[d] = se;
  }
}

// P = bc_last*P + A*S - GM ;  S = ce_last*S - GS
__global__ void update_k(float* __restrict__ P, float* __restrict__ S,
                         const float* __restrict__ GM, const float* __restrict__ GS,
                         const float* __restrict__ scal, int n) {
  int i = blockIdx.x * blockDim.x + threadIdx.x;
  if (i < n) {
    float p = P[i], s = S[i];
    P[i] = scal[0] * p + scal[1] * s - GM[i];
    S[i] = scal[2] * s - GS[i];
  }
}

// out = q + rms(y)*ln  (one block per row)
__global__ __launch_bounds__(256) void final_out_k(
    const float* __restrict__ Q, const float* __restrict__ Y,
    const float* __restrict__ ln, float* __restrict__ out) {
  __shared__ float red[256];
  int row = blockIdx.x, tid = threadIdx.x;
  size_t base = (size_t)row * Dd;
  float y0 = Y[base + tid], y1 = Y[base + tid + 256];
  float ss = block_reduce_sum(y0 * y0 + y1 * y1, red);
  float r = rsqrtf(ss / (float)Dd + EPS);
  out[base + tid]       = Q[base + tid]       + y0 * r * ln[tid];
  out[base + tid + 256] = Q[base + tid + 256] + y1 * r * ln[tid + 256];
}

} // namespace

extern "C" void kernel_launch(void* const* d_in, const int* in_sizes, int n_in,
                              void* d_out, int out_size, void* d_ws, size_t ws_size,
                              hipStream_t stream)
{
  const float* x   = (const float*)d_in[0];
  const float* wq  = (const float*)d_in[1];
  const float* wkw = (const float*)d_in[2];
  const float* wvw = (const float*)d_in[3];
  const float* qn  = (const float*)d_in[4];
  const float* kn  = (const float*)d_in[5];
  const float* aw  = (const float*)d_in[6];
  const float* ab  = (const float*)d_in[7];
  const float* tw  = (const float*)d_in[8];
  const float* tb  = (const float*)d_in[9];
  const float* ew  = (const float*)d_in[10];
  const float* eb  = (const float*)d_in[11];
  const float* mw0 = (const float*)d_in[12];
  const float* mw1 = (const float*)d_in[13];
  const float* mln = (const float*)d_in[14];
  float* out = (float*)d_out;

  float* p = (float*)d_ws;
  auto alloc = [&](size_t n) { float* r = p; p += n; return r; };

  float* w0c  = alloc((size_t)Ii * Dd);
  float* w1c  = alloc((size_t)Dd * Ii);
  float* Sw0  = alloc((size_t)Ii * Dd);
  float* Sw1  = alloc((size_t)Dd * Ii);
  float* Gw0M = alloc((size_t)Ii * Dd);
  float* Gw0S = alloc((size_t)Ii * Dd);
  float* Gw1M = alloc((size_t)Dd * Ii);
  float* Gw1S = alloc((size_t)Dd * Ii);
  float* lnc  = alloc(Dd);
  float* Sln  = alloc(Dd);
  float* GlnM = alloc(Dd);
  float* GlnS = alloc(Dd);
  float* xc   = alloc((size_t)RowsC * Dd);
  float* Krows= alloc((size_t)RowsC * Dd);
  float* Vrows= alloc((size_t)RowsC * Dd);
  float* tmpKV= alloc((size_t)RowsC * Dd);
  float* Ybuf = alloc((size_t)RowsC * Dd);
  float* dY   = alloc((size_t)RowsC * Dd);
  float* gyr  = alloc((size_t)RowsC * Dd);
  float* Z0   = alloc((size_t)RowsC * Ii);
  float* Hbuf = alloc((size_t)RowsC * Ii);
  float* dH   = alloc((size_t)RowsC * Ii);
  float* alv  = alloc(Cc);
  float* thv  = alloc(Cc);
  float* etv  = alloc(Cc);
  float* wBv  = alloc(RowsC);
  float* wEv  = alloc(RowsC);
  float* scal = alloc(4);
  float* Qb   = alloc((size_t)RowsAll * Dd);
  float* Hr   = alloc((size_t)RowsAll * Ii);
  float* Yr   = alloc((size_t)RowsAll * Dd);

  auto gemm = [&](const float* A, const float* Bm, float* Cm,
                  int M, int N, int K, int sma, int ska, int skb, int snb,
                  int ldc, const float* kw, int act) {
    dim3 g(N / 64, M / 64), b(256);
    if (act) gemm_k<1><<<g, b, 0, stream>>>(A, Bm, Cm, M, N, K, sma, ska, skb, snb, ldc, kw);
    else     gemm_k<0><<<g, b, 0, stream>>>(A, Bm, Cm, M, N, K, sma, ska, skb, snb, ldc, kw);
  };

  // init memory params + zero surprise
  hipMemcpyAsync(w0c, mw0, (size_t)Ii * Dd * 4, hipMemcpyDeviceToDevice, stream);
  hipMemcpyAsync(w1c, mw1, (size_t)Dd * Ii * 4, hipMemcpyDeviceToDevice, stream);
  hipMemcpyAsync(lnc, mln, (size_t)Dd * 4, hipMemcpyDeviceToDevice, stream);
  hipMemsetAsync(Sw0, 0, (size_t)Ii * Dd * 4, stream);
  hipMemsetAsync(Sw1, 0, (size_t)Dd * Ii * 4, stream);
  hipMemsetAsync(Sln, 0, (size_t)Dd * 4, stream);

  for (int ci = 0; ci < nCk; ++ci) {
    gather_k<<<RowsC, 256, 0, stream>>>(x, xc, ci);
    gates_k<<<Cc, 256, 0, stream>>>(xc, aw, ab, tw, tb, ew, eb, alv, thv, etv);
    gate_scan_k<<<1, 64, 0, stream>>>(alv, etv, wBv, wEv, scal);

    // k = rms(silu(xc @ wk^T)) * kn ; v = silu(xc @ wv^T)
    gemm(xc, wkw, tmpKV, RowsC, Dd, Dd, Dd, 1, 1, Dd, Dd, nullptr, 0);
    silu_rms_k<<<RowsC, 256, 0, stream>>>(tmpKV, Krows, kn);
    gemm(xc, wvw, tmpKV, RowsC, Dd, Dd, Dd, 1, 1, Dd, Dd, nullptr, 0);
    silu_k<<<(RowsC * Dd) / 256, 256, 0, stream>>>(tmpKV, Vrows, RowsC * Dd);

    // forward MLP
    gemm(Krows, w0c, Z0, RowsC, Ii, Dd, Dd, 1, 1, Dd, Ii, nullptr, 0);
    silu_k<<<(RowsC * Ii) / 256, 256, 0, stream>>>(Z0, Hbuf, RowsC * Ii);
    gemm(Hbuf, w1c, Ybuf, RowsC, Dd, Ii, Ii, 1, 1, Ii, Dd, nullptr, 0);

    // backward
    loss_back_k<<<RowsC, 256, 0, stream>>>(Krows, Vrows, Ybuf, lnc, thv, dY, gyr);
    colsum_k<<<2, 256, 0, stream>>>(gyr, wBv, wEv, GlnM, GlnS);
    gemm(dY, w1c, dH, RowsC, Ii, Dd, Dd, 1, Ii, 1, Ii, nullptr, 0);
    dz_k<<<(RowsC * Ii) / 256, 256, 0, stream>>>(dH, Z0, RowsC * Ii);

    // weighted grad GEMMs
    gemm(dY, Hbuf, Gw1M, Dd, Ii, RowsC, 1, Dd, Ii, 1, Ii, wBv, 0);
    gemm(dY, Hbuf, Gw1S, Dd, Ii, RowsC, 1, Dd, Ii, 1, Ii, wEv, 0);
    gemm(dH, Krows, Gw0M, Ii, Dd, RowsC, 1, Ii, Dd, 1, Dd, wBv, 0);
    gemm(dH, Krows, Gw0S, Ii, Dd, RowsC, 1, Ii, Dd, 1, Dd, wEv, 0);

    // updates
    update_k<<<(Ii * Dd) / 256, 256, 0, stream>>>(w0c, Sw0, Gw0M, Gw0S, scal, Ii * Dd);
    update_k<<<(Dd * Ii) / 256, 256, 0, stream>>>(w1c, Sw1, Gw1M, Gw1S, scal, Dd * Ii);
    update_k<<<2, 256, 0, stream>>>(lnc, Sln, GlnM, GlnS, scal, Dd);
  }

  // retrieval: q = rms(silu(x @ wq^T)) * qn ; out = q + rms(silu(q@w0F^T)@w1F^T)*lnF
  gemm(x, wq, Yr, RowsAll, Dd, Dd, Dd, 1, 1, Dd, Dd, nullptr, 0);
  silu_rms_k<<<RowsAll, 256, 0, stream>>>(Yr, Qb, qn);
  gemm(Qb, w0c, Hr, RowsAll, Ii, Dd, Dd, 1, 1, Dd, Ii, nullptr, 1);   // fused silu
  gemm(Hr, w1c, Yr, RowsAll, Dd, Ii, Ii, 1, 1, Ii, Dd, nullptr, 0);
  final_out_k<<<RowsAll, 256, 0, stream>>>(Qb, Yr, lnc, out);
}

// Round 2
// 1433.317 us; speedup vs baseline: 2.6844x; 2.6844x over previous
//
#include <hip/hip_runtime.h>
#include <math.h>

#define EPS 1e-6f

namespace {

typedef unsigned short u16;
typedef unsigned int u32;
typedef __bf16 bf16x8 __attribute__((ext_vector_type(8)));
typedef float f32x4 __attribute__((ext_vector_type(4)));

constexpr int Bb = 4, Ss = 512, Dd = 512, Ii = 1024, Cc = 64;
constexpr int nCk = Ss / Cc;           // 8 chunks
constexpr int RowsC = Bb * Cc;         // 256
constexpr int RowsAll = Bb * Ss;       // 2048

__device__ __forceinline__ float sigmoidf_(float x) { return 1.f / (1.f + expf(-x)); }
__device__ __forceinline__ float siluf_(float x)    { return x / (1.f + expf(-x)); }

__device__ __forceinline__ u16 f2bf(float f) {
  u32 u = __float_as_uint(f);
  u32 r = u + 0x7fffu + ((u >> 16) & 1u);
  return (u16)(r >> 16);
}

__device__ __forceinline__ void llds16(const u16* g, u16* l) {
  __builtin_amdgcn_global_load_lds((__attribute__((address_space(1))) void*)g,
                                   (__attribute__((address_space(3))) void*)l,
                                   16, 0, 0);
}

__device__ __forceinline__ float block_reduce_sum(float v, float* red) {
  int tid = threadIdx.x;
  red[tid] = v; __syncthreads();
  for (int s = 128; s > 0; s >>= 1) {
    if (tid < s) red[tid] += red[tid + s];
    __syncthreads();
  }
  float r = red[0]; __syncthreads();
  return r;
}

// ---------------------------------------------------------------------------
// MFMA bf16 GEMM:  C[M,N] = epi( sum_k A[m,k] * Bt[n,k] )
// A: bf16 [M][K] row-major.  Bt: bf16 [N][K] row-major (i.e. B^T).
// TS = tile size (BM=BN=TS), BK=64, 256 threads = 4 waves in 2x2.
// global_load_lds(16B) linear LDS dest + inverse-swizzled source;
// ds_read_b128 with chunk ^= (row&7) swizzle -> conflict-free.
// EPI: 0 C0=v | 1 C0=silu(v) | 2 C0=v,C1=silu(v),Cb=bf(silu(v))
//      3 C0=v*silu'(Z) | 4 Cb=bf(silu(v))
// ---------------------------------------------------------------------------
template<int TS, int EPI>
__global__ __launch_bounds__(256) void mgemm_k(
    const u16* __restrict__ A, const u16* __restrict__ Bt,
    float* __restrict__ C0, float* __restrict__ C1, u16* __restrict__ Cb,
    const float* __restrict__ Z,
    int M, int N, int K)
{
  constexpr int BK = 64;
  constexpr int FR = TS / 32;                 // frags per wave dim (2 or 4)
  constexpr int NISS = (TS * BK * 2) / 4096;  // 16B issues per tile (2 or 4)
  __shared__ u16 As[TS * BK];
  __shared__ u16 Bs[TS * BK];

  const int tid = threadIdx.x;
  const int l = tid & 63;
  const int lr = l & 15, lq = l >> 4;
  const int w = tid >> 6;
  const int wr = w >> 1, wc = w & 1;
  const int bm = blockIdx.y * TS, bn = blockIdx.x * TS;

  f32x4 acc[FR][FR];
  #pragma unroll
  for (int i = 0; i < FR; ++i)
    #pragma unroll
    for (int j = 0; j < FR; ++j)
      acc[i][j] = f32x4{0.f, 0.f, 0.f, 0.f};

  for (int k0 = 0; k0 < K; k0 += BK) {
    #pragma unroll
    for (int i = 0; i < NISS; ++i) {
      int e = i * 256 + tid;                    // 16B-chunk id within tile
      int r = e >> 3;                           // 8 chunks per 64-elem row
      int c = (e & 7) ^ (r & 7);                // inverse swizzle on source
      llds16(A  + (size_t)(bm + r) * K + k0 + c * 8, As + e * 8);
      llds16(Bt + (size_t)(bn + r) * K + k0 + c * 8, Bs + e * 8);
    }
    __syncthreads();

    #pragma unroll
    for (int kk = 0; kk < 2; ++kk) {
      bf16x8 av[FR], bv[FR];
      #pragma unroll
      for (int m = 0; m < FR; ++m) {
        int r = wr * (TS / 2) + m * 16 + lr;
        int c = (kk * 4 + lq) ^ (r & 7);
        av[m] = *reinterpret_cast<const bf16x8*>(&As[r * BK + c * 8]);
      }
      #pragma unroll
      for (int n = 0; n < FR; ++n) {
        int r = wc * (TS / 2) + n * 16 + lr;
        int c = (kk * 4 + lq) ^ (r & 7);
        bv[n] = *reinterpret_cast<const bf16x8*>(&Bs[r * BK + c * 8]);
      }
      #pragma unroll
      for (int m = 0; m < FR; ++m)
        #pragma unroll
        for (int n = 0; n < FR; ++n)
          acc[m][n] = __builtin_amdgcn_mfma_f32_16x16x32_bf16(av[m], bv[n], acc[m][n], 0, 0, 0);
    }
    __syncthreads();
  }

  // epilogue: C/D layout col = lane&15, row = (lane>>4)*4 + reg
  #pragma unroll
  for (int m = 0; m < FR; ++m) {
    int gr0 = bm + wr * (TS / 2) + m * 16 + lq * 4;
    #pragma unroll
    for (int n = 0; n < FR; ++n) {
      int gc = bn + wc * (TS / 2) + n * 16 + lr;
      #pragma unroll
      for (int q = 0; q < 4; ++q) {
        size_t idx = (size_t)(gr0 + q) * N + gc;
        float v = acc[m][n][q];
        if (EPI == 0) {
          C0[idx] = v;
        } else if (EPI == 1) {
          C0[idx] = siluf_(v);
        } else if (EPI == 2) {
          C0[idx] = v;
          float s = siluf_(v);
          C1[idx] = s;
          Cb[idx] = f2bf(s);
        } else if (EPI == 3) {
          float z = Z[idx];
          float sg = 1.f / (1.f + expf(-z));
          C0[idx] = v * sg * (1.f + z * (1.f - sg));
        } else {
          Cb[idx] = f2bf(siluf_(v));
        }
      }
    }
  }
}

// fp32 -> bf16 row-major convert (n % 4 == 0)
__global__ void conv_k(const float* __restrict__ s, u16* __restrict__ d, int n) {
  int i = (blockIdx.x * 256 + threadIdx.x) * 4;
  if (i < n) {
    float4 v = *reinterpret_cast<const float4*>(s + i);
    ushort4 o;
    o.x = f2bf(v.x); o.y = f2bf(v.y); o.z = f2bf(v.z); o.w = f2bf(v.w);
    *reinterpret_cast<ushort4*>(d + i) = o;
  }
}

// Tiled transpose-convert: src fp32 [R][C] -> dst bf16 [C][R], optional
// per-src-row weights (dual output shares one read of src).
__global__ __launch_bounds__(256) void trans2_k(
    const float* __restrict__ src, int R, int C,
    u16* __restrict__ d1, const float* __restrict__ w1,
    u16* __restrict__ d2, const float* __restrict__ w2)
{
  __shared__ float t1[64][65];
  __shared__ float t2[64][65];
  const int bc = blockIdx.x * 64, br = blockIdx.y * 64;
  const int tid = threadIdx.x;
  #pragma unroll
  for (int i = 0; i < 16; ++i) {
    int e = tid + i * 256;
    int r = e >> 6, c = e & 63;
    float v = src[(size_t)(br + r) * C + bc + c];
    t1[r][c] = w1 ? v * w1[br + r] : v;
    if (d2) t2[r][c] = v * w2[br + r];
  }
  __syncthreads();
  #pragma unroll
  for (int i = 0; i < 16; ++i) {
    int e = tid + i * 256;
    int rr = e >> 6, cc = e & 63;
    size_t o = (size_t)(bc + rr) * R + br + cc;
    d1[o] = f2bf(t1[cc][rr]);
    if (d2) d2[o] = f2bf(t2[cc][rr]);
  }
}

// gather chunk ci of x into contiguous [256, D] rows, fp32 + bf16
__global__ __launch_bounds__(256) void gather_k(const float* __restrict__ x,
                                                float* __restrict__ xc,
                                                u16* __restrict__ xcb, int ci) {
  int row = blockIdx.x;            // b*64+t
  int b = row >> 6, t = row & 63;
  const float* src = x + ((size_t)b * Ss + (size_t)ci * Cc + t) * Dd;
  size_t base = (size_t)row * Dd;
  for (int d = threadIdx.x; d < Dd; d += 256) {
    float v = src[d];
    xc[base + d] = v;
    xcb[base + d] = f2bf(v);
  }
}

// per-token gates: al/th/et  (one block per token)
__global__ __launch_bounds__(256) void gates_k(
    const float* __restrict__ xc,
    const float* __restrict__ aw, const float* __restrict__ ab,
    const float* __restrict__ tw, const float* __restrict__ tb,
    const float* __restrict__ ew, const float* __restrict__ eb,
    float* __restrict__ al, float* __restrict__ th, float* __restrict__ et)
{
  __shared__ float red[256];
  int t = blockIdx.x, tid = threadIdx.x;
  float sa = 0.f, st = 0.f, se = 0.f;
  for (int b = 0; b < Bb; ++b) {
    const float* xr = xc + (size_t)(b * Cc + t) * Dd;
    for (int d = tid; d < Dd; d += 256) {
      float xv = xr[d];
      sa += xv * aw[d]; st += xv * tw[d]; se += xv * ew[d];
    }
  }
  sa = block_reduce_sum(sa, red);
  st = block_reduce_sum(st, red);
  se = block_reduce_sum(se, red);
  if (tid == 0) {
    al[t] = sigmoidf_(sa + Bb * ab[0]);
    th[t] = sigmoidf_(st + Bb * tb[0]) * 0.01f;
    et[t] = sigmoidf_(se + Bb * eb[0]);
  }
}

// sequential length-64 scans for update weights
__global__ void gate_scan_k(const float* __restrict__ al, const float* __restrict__ et,
                            float* __restrict__ wB, float* __restrict__ wE,
                            float* __restrict__ scal)
{
  if (threadIdx.x != 0 || blockIdx.x != 0) return;
  float beta[Cc], wb[Cc], ce[Cc], E[Cc], T[Cc];
  for (int i = 0; i < Cc; ++i) beta[i] = 1.f - al[i];
  wb[Cc - 1] = 1.f;
  for (int m = Cc - 2; m >= 0; --m) wb[m] = wb[m + 1] * beta[m + 1];
  float bc_last = wb[0] * beta[0];
  float p = 1.f, A = 0.f;
  for (int m = 0; m < Cc; ++m) { p *= et[m]; ce[m] = p; A += wb[m] * ce[m]; }
  E[Cc - 1] = 1.f; T[Cc - 1] = 1.f;
  for (int n = Cc - 2; n >= 0; --n) {
    E[n] = E[n + 1] * et[n + 1];
    T[n] = wb[n] + et[n + 1] * T[n + 1];
  }
  for (int b = 0; b < Bb; ++b)
    for (int t = 0; t < Cc; ++t) { wB[b * Cc + t] = T[t]; wE[b * Cc + t] = E[t]; }
  scal[0] = bc_last; scal[1] = A; scal[2] = ce[Cc - 1];
}

// out = rms(silu(in)) * nw,  fp32 + bf16 (one block per row, D=512)
__global__ __launch_bounds__(256) void silu_rms_k(const float* __restrict__ in,
                                                  float* __restrict__ out,
                                                  u16* __restrict__ outb,
                                                  const float* __restrict__ nw)
{
  __shared__ float red[256];
  int row = blockIdx.x, tid = threadIdx.x;
  const float* ir = in + (size_t)row * Dd;
  float s0 = siluf_(ir[tid]), s1 = siluf_(ir[tid + 256]);
  float ss = block_reduce_sum(s0 * s0 + s1 * s1, red);
  float r = rsqrtf(ss / (float)Dd + EPS);
  float v0 = s0 * r * nw[tid], v1 = s1 * r * nw[tid + 256];
  size_t base = (size_t)row * Dd;
  out[base + tid] = v0;        outb[base + tid] = f2bf(v0);
  out[base + tid + 256] = v1;  outb[base + tid + 256] = f2bf(v1);
}

// per-row loss backward: dY (fp32 + bf16) and gyr
__global__ __launch_bounds__(256) void loss_back_k(
    const float* __restrict__ Kr, const float* __restrict__ Vr,
    const float* __restrict__ Y, const float* __restrict__ ln,
    const float* __restrict__ th,
    float* __restrict__ dY, u16* __restrict__ dYb, float* __restrict__ gyr)
{
  __shared__ float red[256];
  int row = blockIdx.x, tid = threadIdx.x;
  int t = row & 63;
  size_t base = (size_t)row * Dd;
  float y0 = Y[base + tid], y1 = Y[base + tid + 256];
  float ss = block_reduce_sum(y0 * y0 + y1 * y1, red);
  float r = rsqrtf(ss / (float)Dd + EPS);
  float c = 2.f * th[t] / (float)Dd;
  float ln0 = ln[tid], ln1 = ln[tid + 256];
  float x0 = Kr[base + tid], x1 = Kr[base + tid + 256];
  float t0 = Vr[base + tid], t1 = Vr[base + tid + 256];
  float g0 = c * ((x0 + y0 * r * ln0) - t0);
  float g1 = c * ((x1 + y1 * r * ln1) - t1);
  float s = block_reduce_sum(g0 * ln0 * y0 + g1 * ln1 * y1, red);
  float coef = r * r * r * s / (float)Dd;
  float d0 = r * g0 * ln0 - coef * y0;
  float d1 = r * g1 * ln1 - coef * y1;
  dY[base + tid] = d0;        dYb[base + tid] = f2bf(d0);
  dY[base + tid + 256] = d1;  dYb[base + tid + 256] = f2bf(d1);
  gyr[base + tid] = g0 * y0 * r;
  gyr[base + tid + 256] = g1 * y1 * r;
}

// Gln[d] = sum_r w[r]*gyr[r,d]
__global__ void colsum_k(const float* __restrict__ gyr,
                         const float* __restrict__ wB, const float* __restrict__ wE,
                         float* __restrict__ GlnM, float* __restrict__ GlnS) {
  int d = blockIdx.x * blockDim.x + threadIdx.x;
  if (d < Dd) {
    float sm = 0.f, se = 0.f;
    for (int r = 0; r < RowsC; ++r) {
      float v = gyr[(size_t)r * Dd + d];
      sm += wB[r] * v; se += wE[r] * v;
    }
    GlnM[d] = sm; GlnS[d] = se;
  }
}

// elementwise param update + bf16 copy (w0)
__global__ void updw_k(float* __restrict__ P, float* __restrict__ S,
                       const float* __restrict__ GM, const float* __restrict__ GS,
                       const float* __restrict__ scal, u16* __restrict__ Pb, int n) {
  int i = blockIdx.x * blockDim.x + threadIdx.x;
  if (i < n) {
    float p = P[i], s = S[i];
    float np = scal[0] * p + scal[1] * s - GM[i];
    float ns = scal[2] * s - GS[i];
    P[i] = np; S[i] = ns; Pb[i] = f2bf(np);
  }
}

// tiled param update + bf16 copy + bf16 transposed copy (w1)
__global__ __launch_bounds__(256) void updwt_k(
    float* __restrict__ P, float* __restrict__ S,
    const float* __restrict__ GM, const float* __restrict__ GS,
    const float* __restrict__ scal,
    u16* __restrict__ Pb, u16* __restrict__ PbT, int R, int C)
{
  __shared__ float t[64][65];
  const int bc = blockIdx.x * 64, br = blockIdx.y * 64;
  const int tid = threadIdx.x;
  float s0 = scal[0], s1 = scal[1], s2 = scal[2];
  #pragma unroll
  for (int i = 0; i < 16; ++i) {
    int e = tid + i * 256;
    int r = e >> 6, c = e & 63;
    size_t idx = (size_t)(br + r) * C + bc + c;
    float p = P[idx], s = S[idx];
    float np = s0 * p + s1 * s - GM[idx];
    float ns = s2 * s - GS[idx];
    P[idx] = np; S[idx] = ns; Pb[idx] = f2bf(np);
    t[r][c] = np;
  }
  __syncthreads();
  #pragma unroll
  for (int i = 0; i < 16; ++i) {
    int e = tid + i * 256;
    int rr = e >> 6, cc = e & 63;
    PbT[(size_t)(bc + rr) * R + br + cc] = f2bf(t[cc][rr]);
  }
}

// ln update (tiny)
__global__ void updln_k(float* __restrict__ P, float* __restrict__ S,
                        const float* __restrict__ GM, const float* __restrict__ GS,
                        const float* __restrict__ scal, int n) {
  int i = blockIdx.x * blockDim.x + threadIdx.x;
  if (i < n) {
    float p = P[i], s = S[i];
    P[i] = scal[0] * p + scal[1] * s - GM[i];
    S[i] = scal[2] * s - GS[i];
  }
}

// out = q + rms(y)*ln
__global__ __launch_bounds__(256) void final_out_k(
    const float* __restrict__ Q, const float* __restrict__ Y,
    const float* __restrict__ ln, float* __restrict__ out) {
  __shared__ float red[256];
  int row = blockIdx.x, tid = threadIdx.x;
  size_t base = (size_t)row * Dd;
  float y0 = Y[base + tid], y1 = Y[base + tid + 256];
  float ss = block_reduce_sum(y0 * y0 + y1 * y1, red);
  float r = rsqrtf(ss / (float)Dd + EPS);
  out[base + tid]       = Q[base + tid]       + y0 * r * ln[tid];
  out[base + tid + 256] = Q[base + tid + 256] + y1 * r * ln[tid + 256];
}

} // namespace

extern "C" void kernel_launch(void* const* d_in, const int* in_sizes, int n_in,
                              void* d_out, int out_size, void* d_ws, size_t ws_size,
                              hipStream_t stream)
{
  const float* x   = (const float*)d_in[0];
  const float* wq  = (const float*)d_in[1];
  const float* wkw = (const float*)d_in[2];
  const float* wvw = (const float*)d_in[3];
  const float* qn  = (const float*)d_in[4];
  const float* kn  = (const float*)d_in[5];
  const float* aw  = (const float*)d_in[6];
  const float* ab  = (const float*)d_in[7];
  const float* tw  = (const float*)d_in[8];
  const float* tb  = (const float*)d_in[9];
  const float* ew  = (const float*)d_in[10];
  const float* eb  = (const float*)d_in[11];
  const float* mw0 = (const float*)d_in[12];
  const float* mw1 = (const float*)d_in[13];
  const float* mln = (const float*)d_in[14];
  float* out = (float*)d_out;

  float* p = (float*)d_ws;
  auto alloc = [&](size_t n) { float* r = p; p += n; return r; };

  // fp32 buffers
  float* w0c  = alloc((size_t)Ii * Dd);
  float* Sw0  = alloc((size_t)Ii * Dd);
  float* Gw0M = alloc((size_t)Ii * Dd);
  float* Gw0S = alloc((size_t)Ii * Dd);
  float* w1c  = alloc((size_t)Dd * Ii);
  float* Sw1  = alloc((size_t)Dd * Ii);
  float* Gw1M = alloc((size_t)Dd * Ii);
  float* Gw1S = alloc((size_t)Dd * Ii);
  float* lnc  = alloc(Dd);
  float* Sln  = alloc(Dd);
  float* GlnM = alloc(Dd);
  float* GlnS = alloc(Dd);
  float* xc   = alloc((size_t)RowsC * Dd);
  float* tmpK = alloc((size_t)RowsC * Dd);
  float* Krows= alloc((size_t)RowsC * Dd);
  float* Vrows= alloc((size_t)RowsC * Dd);
  float* Ybuf = alloc((size_t)RowsC * Dd);
  float* dY   = alloc((size_t)RowsC * Dd);
  float* gyr  = alloc((size_t)RowsC * Dd);
  float* Z0   = alloc((size_t)RowsC * Ii);
  float* Hbuf = alloc((size_t)RowsC * Ii);
  float* dHb  = alloc((size_t)RowsC * Ii);
  float* alv  = alloc(Cc);
  float* thv  = alloc(Cc);
  float* etv  = alloc(Cc);
  float* wBv  = alloc(RowsC);
  float* wEv  = alloc(RowsC);
  float* scal = alloc(4);
  float* Qb   = alloc((size_t)RowsAll * Dd);
  float* Yr   = alloc((size_t)RowsAll * Dd);

  // bf16 (u16) buffers
  u16* q16 = (u16*)p;
  auto alloc16 = [&](size_t n) { u16* r = q16; q16 += n; return r; };
  u16* x_bf    = alloc16((size_t)RowsAll * Dd);
  u16* wq_bf   = alloc16((size_t)Dd * Dd);
  u16* wk_bf   = alloc16((size_t)Dd * Dd);
  u16* wv_bf   = alloc16((size_t)Dd * Dd);
  u16* w0c_bf  = alloc16((size_t)Ii * Dd);
  u16* w1c_bf  = alloc16((size_t)Dd * Ii);
  u16* w1cT_bf = alloc16((size_t)Ii * Dd);
  u16* xc_bf   = alloc16((size_t)RowsC * Dd);
  u16* K_bf    = alloc16((size_t)RowsC * Dd);
  u16* KT      = alloc16((size_t)Dd * RowsC);
  u16* H_bf    = alloc16((size_t)RowsC * Ii);
  u16* Ht      = alloc16((size_t)Ii * RowsC);
  u16* dY_bf   = alloc16((size_t)RowsC * Dd);
  u16* dYtW    = alloc16((size_t)Dd * RowsC);
  u16* dYtE    = alloc16((size_t)Dd * RowsC);
  u16* dHtW    = alloc16((size_t)Ii * RowsC);
  u16* dHtE    = alloc16((size_t)Ii * RowsC);
  u16* Qb_bf   = alloc16((size_t)RowsAll * Dd);
  u16* Hr_bf   = alloc16((size_t)RowsAll * Ii);

  // ---- init: fp32 masters + zero momentum + bf16 copies of constants
  hipMemcpyAsync(w0c, mw0, (size_t)Ii * Dd * 4, hipMemcpyDeviceToDevice, stream);
  hipMemcpyAsync(w1c, mw1, (size_t)Dd * Ii * 4, hipMemcpyDeviceToDevice, stream);
  hipMemcpyAsync(lnc, mln, (size_t)Dd * 4, hipMemcpyDeviceToDevice, stream);
  hipMemsetAsync(Sw0, 0, (size_t)Ii * Dd * 4, stream);
  hipMemsetAsync(Sw1, 0, (size_t)Dd * Ii * 4, stream);
  hipMemsetAsync(Sln, 0, (size_t)Dd * 4, stream);

  conv_k<<<(Dd * Dd) / 1024, 256, 0, stream>>>(wq, wq_bf, Dd * Dd);
  conv_k<<<(Dd * Dd) / 1024, 256, 0, stream>>>(wkw, wk_bf, Dd * Dd);
  conv_k<<<(Dd * Dd) / 1024, 256, 0, stream>>>(wvw, wv_bf, Dd * Dd);
  conv_k<<<(Ii * Dd) / 1024, 256, 0, stream>>>(mw0, w0c_bf, Ii * Dd);
  conv_k<<<(Dd * Ii) / 1024, 256, 0, stream>>>(mw1, w1c_bf, Dd * Ii);
  trans2_k<<<dim3(Ii / 64, Dd / 64), 256, 0, stream>>>(mw1, Dd, Ii, w1cT_bf, nullptr, nullptr, nullptr);
  conv_k<<<(RowsAll * Dd) / 1024, 256, 0, stream>>>(x, x_bf, RowsAll * Dd);

  for (int ci = 0; ci < nCk; ++ci) {
    gather_k<<<RowsC, 256, 0, stream>>>(x, xc, xc_bf, ci);
    gates_k<<<Cc, 256, 0, stream>>>(xc, aw, ab, tw, tb, ew, eb, alv, thv, etv);
    gate_scan_k<<<1, 64, 0, stream>>>(alv, etv, wBv, wEv, scal);

    // K/V projections
    mgemm_k<64, 0><<<dim3(Dd / 64, RowsC / 64), 256, 0, stream>>>(
        xc_bf, wk_bf, tmpK, nullptr, nullptr, nullptr, RowsC, Dd, Dd);
    silu_rms_k<<<RowsC, 256, 0, stream>>>(tmpK, Krows, K_bf, kn);
    mgemm_k<64, 1><<<dim3(Dd / 64, RowsC / 64), 256, 0, stream>>>(
        xc_bf, wv_bf, Vrows, nullptr, nullptr, nullptr, RowsC, Dd, Dd);

    // forward MLP
    mgemm_k<64, 2><<<dim3(Ii / 64, RowsC / 64), 256, 0, stream>>>(
        K_bf, w0c_bf, Z0, Hbuf, H_bf, nullptr, RowsC, Ii, Dd);
    mgemm_k<64, 0><<<dim3(Dd / 64, RowsC / 64), 256, 0, stream>>>(
        H_bf, w1c_bf, Ybuf, nullptr, nullptr, nullptr, RowsC, Dd, Ii);

    // backward
    loss_back_k<<<RowsC, 256, 0, stream>>>(Krows, Vrows, Ybuf, lnc, thv, dY, dY_bf, gyr);
    colsum_k<<<2, 256, 0, stream>>>(gyr, wBv, wEv, GlnM, GlnS);
    mgemm_k<64, 3><<<dim3(Ii / 64, RowsC / 64), 256, 0, stream>>>(
        dY_bf, w1cT_bf, dHb, nullptr, nullptr, Z0, RowsC, Ii, Dd);

    // transposed bf16 copies (weights folded)
    trans2_k<<<dim3(Dd / 64, RowsC / 64), 256, 0, stream>>>(Krows, RowsC, Dd, KT, nullptr, nullptr, nullptr);
    trans2_k<<<dim3(Ii / 64, RowsC / 64), 256, 0, stream>>>(Hbuf, RowsC, Ii, Ht, nullptr, nullptr, nullptr);
    trans2_k<<<dim3(Dd / 64, RowsC / 64), 256, 0, stream>>>(dY, RowsC, Dd, dYtW, wBv, dYtE, wEv);
    trans2_k<<<dim3(Ii / 64, RowsC / 64), 256, 0, stream>>>(dHb, RowsC, Ii, dHtW, wBv, dHtE, wEv);

    // weighted grad GEMMs
    mgemm_k<64, 0><<<dim3(Ii / 64, Dd / 64), 256, 0, stream>>>(
        dYtW, Ht, Gw1M, nullptr, nullptr, nullptr, Dd, Ii, RowsC);
    mgemm_k<64, 0><<<dim3(Ii / 64, Dd / 64), 256, 0, stream>>>(
        dYtE, Ht, Gw1S, nullptr, nullptr, nullptr, Dd, Ii, RowsC);
    mgemm_k<64, 0><<<dim3(Dd / 64, Ii / 64), 256, 0, stream>>>(
        dHtW, KT, Gw0M, nullptr, nullptr, nullptr, Ii, Dd, RowsC);
    mgemm_k<64, 0><<<dim3(Dd / 64, Ii / 64), 256, 0, stream>>>(
        dHtE, KT, Gw0S, nullptr, nullptr, nullptr, Ii, Dd, RowsC);

    // updates (fused bf16 re-materialization)
    updw_k<<<(Ii * Dd) / 256, 256, 0, stream>>>(w0c, Sw0, Gw0M, Gw0S, scal, w0c_bf, Ii * Dd);
    updwt_k<<<dim3(Ii / 64, Dd / 64), 256, 0, stream>>>(w1c, Sw1, Gw1M, Gw1S, scal, w1c_bf, w1cT_bf, Dd, Ii);
    updln_k<<<2, 256, 0, stream>>>(lnc, Sln, GlnM, GlnS, scal, Dd);
  }

  // retrieval
  mgemm_k<128, 0><<<dim3(Dd / 128, RowsAll / 128), 256, 0, stream>>>(
      x_bf, wq_bf, Yr, nullptr, nullptr, nullptr, RowsAll, Dd, Dd);
  silu_rms_k<<<RowsAll, 256, 0, stream>>>(Yr, Qb, Qb_bf, qn);
  mgemm_k<128, 4><<<dim3(Ii / 128, RowsAll / 128), 256, 0, stream>>>(
      Qb_bf, w0c_bf, nullptr, nullptr, Hr_bf, nullptr, RowsAll, Ii, Dd);
  mgemm_k<128, 0><<<dim3(Dd / 128, RowsAll / 128), 256, 0, stream>>>(
      Hr_bf, w1c_bf, Yr, nullptr, nullptr, nullptr, RowsAll, Dd, Ii);
  final_out_k<<<RowsAll, 256, 0, stream>>>(Qb, Yr, lnc, out);
}

// Round 3
// 729.024 us; speedup vs baseline: 5.2777x; 1.9661x over previous
//
#include <hip/hip_runtime.h>
#include <math.h>

#define EPS 1e-6f

namespace {

typedef unsigned short u16;
typedef unsigned int u32;
typedef __bf16 bf16x8 __attribute__((ext_vector_type(8)));
typedef float f32x4 __attribute__((ext_vector_type(4)));
typedef u16 u16x8 __attribute__((ext_vector_type(8)));

constexpr int Bb = 4, Ss = 512, Dd = 512, Ii = 1024, Cc = 64;
constexpr int nCk = Ss / Cc;           // 8 chunks
constexpr int RowsC = Bb * Cc;         // 256
constexpr int RowsAll = Bb * Ss;       // 2048

__device__ __forceinline__ float sigmoidf_(float x) { return 1.f / (1.f + expf(-x)); }
__device__ __forceinline__ float siluf_(float x)    { return x / (1.f + expf(-x)); }

__device__ __forceinline__ u16 f2bf(float f) {
  u32 u = __float_as_uint(f);
  u32 r = u + 0x7fffu + ((u >> 16) & 1u);
  return (u16)(r >> 16);
}

__device__ __forceinline__ void llds16(const u16* g, u16* l) {
  __builtin_amdgcn_global_load_lds((__attribute__((address_space(1))) void*)g,
                                   (__attribute__((address_space(3))) void*)l,
                                   16, 0, 0);
}

__device__ __forceinline__ float wave_sum(float v) {
  #pragma unroll
  for (int m = 32; m > 0; m >>= 1) v += __shfl_xor(v, m, 64);
  return v;
}

__device__ __forceinline__ float block_reduce_sum(float v, float* red) {
  int tid = threadIdx.x;
  red[tid] = v; __syncthreads();
  for (int s = 128; s > 0; s >>= 1) {
    if (tid < s) red[tid] += red[tid + s];
    __syncthreads();
  }
  float r = red[0]; __syncthreads();
  return r;
}

// ---------------------------------------------------------------------------
// MFMA bf16 GEMM:  C[M,N] = epi( sum_k A[m,k] * Bt[n,k] )
// A: bf16 [M][K] row-major.  Bt: bf16 [N][K] row-major (i.e. B^T).
// TS tile, BK=64, 256 threads = 4 waves in 2x2.
// EPI: 0  C0[idx]=v
//      1  KV-split: gc<Dd -> C0=v (tmpK) ; else C1=silu(v) (Vrows), both ld=Dd
//      2  Z0-GEMM:  C0=v (Z0), Cb=bf(silu(v)) (H_bf), CbT=transposed bf (Ht)
//      3  dH-GEMM:  dh=v*silu'(Z); CbT=bf(dh*wB[row]) ; CbT2=bf(dh*wE[row])
//      4  Cb=bf(silu(v))
// ---------------------------------------------------------------------------
template<int TS, int EPI>
__global__ __launch_bounds__(256) void mgemm_k(
    const u16* __restrict__ A, const u16* __restrict__ Bt,
    float* __restrict__ C0, float* __restrict__ C1,
    u16* __restrict__ Cb, u16* __restrict__ CbT, u16* __restrict__ CbT2,
    const float* __restrict__ Z,
    const float* __restrict__ wB, const float* __restrict__ wE,
    int M, int N, int K)
{
  constexpr int BK = 64;
  constexpr int FR = TS / 32;
  constexpr int NISS = (TS * BK * 2) / 4096;
  __shared__ u16 As[TS * BK];
  __shared__ u16 Bs[TS * BK];

  const int tid = threadIdx.x;
  const int l = tid & 63;
  const int lr = l & 15, lq = l >> 4;
  const int w = tid >> 6;
  const int wr = w >> 1, wc = w & 1;
  const int bm = blockIdx.y * TS, bn = blockIdx.x * TS;

  f32x4 acc[FR][FR];
  #pragma unroll
  for (int i = 0; i < FR; ++i)
    #pragma unroll
    for (int j = 0; j < FR; ++j)
      acc[i][j] = f32x4{0.f, 0.f, 0.f, 0.f};

  for (int k0 = 0; k0 < K; k0 += BK) {
    #pragma unroll
    for (int i = 0; i < NISS; ++i) {
      int e = i * 256 + tid;
      int r = e >> 3;
      int c = (e & 7) ^ (r & 7);
      llds16(A  + (size_t)(bm + r) * K + k0 + c * 8, As + e * 8);
      llds16(Bt + (size_t)(bn + r) * K + k0 + c * 8, Bs + e * 8);
    }
    __syncthreads();

    #pragma unroll
    for (int kk = 0; kk < 2; ++kk) {
      bf16x8 av[FR], bv[FR];
      #pragma unroll
      for (int m = 0; m < FR; ++m) {
        int r = wr * (TS / 2) + m * 16 + lr;
        int c = (kk * 4 + lq) ^ (r & 7);
        av[m] = *reinterpret_cast<const bf16x8*>(&As[r * BK + c * 8]);
      }
      #pragma unroll
      for (int n = 0; n < FR; ++n) {
        int r = wc * (TS / 2) + n * 16 + lr;
        int c = (kk * 4 + lq) ^ (r & 7);
        bv[n] = *reinterpret_cast<const bf16x8*>(&Bs[r * BK + c * 8]);
      }
      #pragma unroll
      for (int m = 0; m < FR; ++m)
        #pragma unroll
        for (int n = 0; n < FR; ++n)
          acc[m][n] = __builtin_amdgcn_mfma_f32_16x16x32_bf16(av[m], bv[n], acc[m][n], 0, 0, 0);
    }
    __syncthreads();
  }

  // epilogue: C/D layout col = lane&15, row = (lane>>4)*4 + reg
  #pragma unroll
  for (int m = 0; m < FR; ++m) {
    int gr0 = bm + wr * (TS / 2) + m * 16 + lq * 4;
    float wbq[4], weq[4];
    if (EPI == 3) {
      #pragma unroll
      for (int q = 0; q < 4; ++q) { wbq[q] = wB[gr0 + q]; weq[q] = wE[gr0 + q]; }
    }
    #pragma unroll
    for (int n = 0; n < FR; ++n) {
      int gc = bn + wc * (TS / 2) + n * 16 + lr;
      ushort4 t1, t2;
      #pragma unroll
      for (int q = 0; q < 4; ++q) {
        float v = acc[m][n][q];
        size_t idx = (size_t)(gr0 + q) * N + gc;
        if (EPI == 0) {
          C0[idx] = v;
        } else if (EPI == 1) {
          if (gc < Dd) C0[(size_t)(gr0 + q) * Dd + gc] = v;
          else         C1[(size_t)(gr0 + q) * Dd + gc - Dd] = siluf_(v);
        } else if (EPI == 2) {
          C0[idx] = v;
          float h = siluf_(v);
          Cb[idx] = f2bf(h);
          ((u16*)&t1)[q] = f2bf(h);
        } else if (EPI == 3) {
          float z = Z[idx];
          float sg = 1.f / (1.f + expf(-z));
          float dh = v * sg * (1.f + z * (1.f - sg));
          ((u16*)&t1)[q] = f2bf(dh * wbq[q]);
          ((u16*)&t2)[q] = f2bf(dh * weq[q]);
        } else if (EPI == 4) {
          Cb[idx] = f2bf(siluf_(v));
        }
      }
      if (EPI == 2) {
        *reinterpret_cast<ushort4*>(&CbT[(size_t)gc * M + gr0]) = t1;
      }
      if (EPI == 3) {
        *reinterpret_cast<ushort4*>(&CbT[(size_t)gc * M + gr0]) = t1;
        *reinterpret_cast<ushort4*>(&CbT2[(size_t)gc * M + gr0]) = t2;
      }
    }
  }
}

// ---------------------------------------------------------------------------
// Dual-weighted grad GEMM + fused parameter update.
// accM = AW^. Bt ; accE = AE^. Bt  (A* : [M][K] bf16, Bt : [N][K] bf16)
// P[idx] = s0*P + s1*S - accM ; S[idx] = s2*S - accE ; Pb = bf(P)
// TR: also PbT[n*M+m] = bf(newP) (transposed copy, packed 4).
// ---------------------------------------------------------------------------
template<bool TR>
__global__ __launch_bounds__(256) void ggemm_k(
    const u16* __restrict__ AW, const u16* __restrict__ AE,
    const u16* __restrict__ Bt,
    float* __restrict__ P, float* __restrict__ Sm,
    u16* __restrict__ Pb, u16* __restrict__ PbT,
    const float* __restrict__ scal,
    int M, int N, int K)
{
  constexpr int TS = 64, BK = 64;
  __shared__ u16 AsW[TS * BK];
  __shared__ u16 AsE[TS * BK];
  __shared__ u16 Bs[TS * BK];

  const int tid = threadIdx.x;
  const int l = tid & 63;
  const int lr = l & 15, lq = l >> 4;
  const int w = tid >> 6;
  const int wr = w >> 1, wc = w & 1;
  const int bm = blockIdx.y * TS, bn = blockIdx.x * TS;

  f32x4 aM[2][2], aE[2][2];
  #pragma unroll
  for (int i = 0; i < 2; ++i)
    #pragma unroll
    for (int j = 0; j < 2; ++j) {
      aM[i][j] = f32x4{0.f, 0.f, 0.f, 0.f};
      aE[i][j] = f32x4{0.f, 0.f, 0.f, 0.f};
    }

  for (int k0 = 0; k0 < K; k0 += BK) {
    #pragma unroll
    for (int i = 0; i < 2; ++i) {
      int e = i * 256 + tid;
      int r = e >> 3;
      int c = (e & 7) ^ (r & 7);
      llds16(AW + (size_t)(bm + r) * K + k0 + c * 8, AsW + e * 8);
      llds16(AE + (size_t)(bm + r) * K + k0 + c * 8, AsE + e * 8);
      llds16(Bt + (size_t)(bn + r) * K + k0 + c * 8, Bs + e * 8);
    }
    __syncthreads();

    #pragma unroll
    for (int kk = 0; kk < 2; ++kk) {
      bf16x8 awv[2], aev[2], bv[2];
      #pragma unroll
      for (int m = 0; m < 2; ++m) {
        int r = wr * 32 + m * 16 + lr;
        int c = (kk * 4 + lq) ^ (r & 7);
        awv[m] = *reinterpret_cast<const bf16x8*>(&AsW[r * BK + c * 8]);
        aev[m] = *reinterpret_cast<const bf16x8*>(&AsE[r * BK + c * 8]);
      }
      #pragma unroll
      for (int n = 0; n < 2; ++n) {
        int r = wc * 32 + n * 16 + lr;
        int c = (kk * 4 + lq) ^ (r & 7);
        bv[n] = *reinterpret_cast<const bf16x8*>(&Bs[r * BK + c * 8]);
      }
      #pragma unroll
      for (int m = 0; m < 2; ++m)
        #pragma unroll
        for (int n = 0; n < 2; ++n) {
          aM[m][n] = __builtin_amdgcn_mfma_f32_16x16x32_bf16(awv[m], bv[n], aM[m][n], 0, 0, 0);
          aE[m][n] = __builtin_amdgcn_mfma_f32_16x16x32_bf16(aev[m], bv[n], aE[m][n], 0, 0, 0);
        }
    }
    __syncthreads();
  }

  float s0 = scal[0], s1 = scal[1], s2 = scal[2];
  #pragma unroll
  for (int m = 0; m < 2; ++m) {
    int gr0 = bm + wr * 32 + m * 16 + lq * 4;
    #pragma unroll
    for (int n = 0; n < 2; ++n) {
      int gc = bn + wc * 32 + n * 16 + lr;
      ushort4 t1;
      #pragma unroll
      for (int q = 0; q < 4; ++q) {
        size_t idx = (size_t)(gr0 + q) * N + gc;
        float p = P[idx], s = Sm[idx];
        float np = s0 * p + s1 * s - aM[m][n][q];
        float ns = s2 * s - aE[m][n][q];
        P[idx] = np; Sm[idx] = ns;
        Pb[idx] = f2bf(np);
        if (TR) ((u16*)&t1)[q] = f2bf(np);
      }
      if (TR) *reinterpret_cast<ushort4*>(&PbT[(size_t)gc * M + gr0]) = t1;
    }
  }
}

// fp32 -> bf16 row-major convert (n % 1024 == 0)
__global__ void conv_k(const float* __restrict__ s, u16* __restrict__ d, int n) {
  int i = (blockIdx.x * 256 + threadIdx.x) * 4;
  if (i < n) {
    float4 v = *reinterpret_cast<const float4*>(s + i);
    ushort4 o;
    o.x = f2bf(v.x); o.y = f2bf(v.y); o.z = f2bf(v.z); o.w = f2bf(v.w);
    *reinterpret_cast<ushort4*>(d + i) = o;
  }
}

// fp32 [R][C] -> bf16 [C][R] (init only)
__global__ __launch_bounds__(256) void transw_k(
    const float* __restrict__ src, int R, int C, u16* __restrict__ dst)
{
  __shared__ float t[64][65];
  const int bc = blockIdx.x * 64, br = blockIdx.y * 64;
  const int tid = threadIdx.x;
  #pragma unroll
  for (int i = 0; i < 16; ++i) {
    int e = tid + i * 256;
    int r = e >> 6, c = e & 63;
    t[r][c] = src[(size_t)(br + r) * C + bc + c];
  }
  __syncthreads();
  #pragma unroll
  for (int i = 0; i < 16; ++i) {
    int e = tid + i * 256;
    int rr = e >> 6, cc = e & 63;
    dst[(size_t)(bc + rr) * R + br + cc] = f2bf(t[cc][rr]);
  }
}

// prep: x -> chunk-ordered bf16 [nCk][256][D]; all-token gates al/th/et [S]
__global__ __launch_bounds__(256) void prep_k(
    const float* __restrict__ x,
    const float* __restrict__ aw, const float* __restrict__ ab,
    const float* __restrict__ tw, const float* __restrict__ tb,
    const float* __restrict__ ew, const float* __restrict__ eb,
    u16* __restrict__ xcb, float* __restrict__ al,
    float* __restrict__ th, float* __restrict__ et)
{
  __shared__ float red[256];
  int s = blockIdx.x, tid = threadIdx.x;
  int ci = s >> 6, t = s & 63;
  float sa = 0.f, st = 0.f, se = 0.f;
  for (int b = 0; b < Bb; ++b) {
    const float* xr = x + ((size_t)b * Ss + s) * Dd;
    u16* dst = xcb + ((size_t)(ci * RowsC + b * Cc + t)) * Dd;
    for (int d = tid; d < Dd; d += 256) {
      float v = xr[d];
      dst[d] = f2bf(v);
      sa += v * aw[d]; st += v * tw[d]; se += v * ew[d];
    }
  }
  sa = block_reduce_sum(sa, red);
  st = block_reduce_sum(st, red);
  se = block_reduce_sum(se, red);
  if (tid == 0) {
    al[s] = sigmoidf_(sa + Bb * ab[0]);
    th[s] = sigmoidf_(st + Bb * tb[0]) * 0.01f;
    et[s] = sigmoidf_(se + Bb * eb[0]);
  }
}

// per-chunk scans (8 blocks, serial on thread 0 — trivial cost)
__global__ void gate_scan_all_k(const float* __restrict__ al, const float* __restrict__ et,
                                float* __restrict__ wB, float* __restrict__ wE,
                                float* __restrict__ scal)
{
  if (threadIdx.x != 0) return;
  int ci = blockIdx.x;
  const float* alc = al + ci * Cc;
  const float* etc_ = et + ci * Cc;
  float beta[Cc], wb[Cc], ce[Cc], E[Cc], T[Cc];
  for (int i = 0; i < Cc; ++i) beta[i] = 1.f - alc[i];
  wb[Cc - 1] = 1.f;
  for (int m = Cc - 2; m >= 0; --m) wb[m] = wb[m + 1] * beta[m + 1];
  float bc_last = wb[0] * beta[0];
  float p = 1.f, A = 0.f;
  for (int m = 0; m < Cc; ++m) { p *= etc_[m]; ce[m] = p; A += wb[m] * ce[m]; }
  E[Cc - 1] = 1.f; T[Cc - 1] = 1.f;
  for (int n = Cc - 2; n >= 0; --n) {
    E[n] = E[n + 1] * etc_[n + 1];
    T[n] = wb[n] + etc_[n + 1] * T[n + 1];
  }
  for (int b = 0; b < Bb; ++b)
    for (int t = 0; t < Cc; ++t) {
      wB[ci * RowsC + b * Cc + t] = T[t];
      wE[ci * RowsC + b * Cc + t] = E[t];
    }
  scal[ci * 4 + 0] = bc_last; scal[ci * 4 + 1] = A; scal[ci * 4 + 2] = ce[Cc - 1];
}

// wave-per-row: out = rms(silu(in))*nw (f32 + bf16 [+ transposed bf16])
template<bool TR>
__global__ __launch_bounds__(256) void silu_rms4_k(
    const float* __restrict__ in, float* __restrict__ out,
    u16* __restrict__ outb, u16* __restrict__ KT,
    const float* __restrict__ nw)
{
  __shared__ u16 lt[4][Dd];
  const int tid = threadIdx.x;
  const int w = tid >> 6, l = tid & 63;
  const int row = blockIdx.x * 4 + w;
  const int d0 = l * 8;
  const float* ir = in + (size_t)row * Dd + d0;
  float v[8];
  *reinterpret_cast<float4*>(&v[0]) = *reinterpret_cast<const float4*>(ir);
  *reinterpret_cast<float4*>(&v[4]) = *reinterpret_cast<const float4*>(ir + 4);
  float ss = 0.f;
  #pragma unroll
  for (int j = 0; j < 8; ++j) { v[j] = siluf_(v[j]); ss += v[j] * v[j]; }
  ss = wave_sum(ss);
  float rr = rsqrtf(ss / (float)Dd + EPS);
  float nv[8];
  *reinterpret_cast<float4*>(&nv[0]) = *reinterpret_cast<const float4*>(nw + d0);
  *reinterpret_cast<float4*>(&nv[4]) = *reinterpret_cast<const float4*>(nw + d0 + 4);
  float y[8];
  u16x8 pb;
  #pragma unroll
  for (int j = 0; j < 8; ++j) { y[j] = v[j] * rr * nv[j]; pb[j] = f2bf(y[j]); }
  float* orow = out + (size_t)row * Dd + d0;
  *reinterpret_cast<float4*>(orow)     = *reinterpret_cast<float4*>(&y[0]);
  *reinterpret_cast<float4*>(orow + 4) = *reinterpret_cast<float4*>(&y[4]);
  *reinterpret_cast<u16x8*>(outb + (size_t)row * Dd + d0) = pb;
  if (TR) {
    #pragma unroll
    for (int j = 0; j < 8; ++j) lt[w][d0 + j] = pb[j];
    __syncthreads();
    int r0 = blockIdx.x * 4;
    for (int d = tid; d < Dd; d += 256) {
      ushort4 pk;
      pk.x = lt[0][d]; pk.y = lt[1][d]; pk.z = lt[2][d]; pk.w = lt[3][d];
      *reinterpret_cast<ushort4*>(&KT[(size_t)d * RowsC + r0]) = pk;
    }
  }
}

// wave-per-row loss backward: dY_bf (row-major), dYtW/dYtE (transposed,
// weighted, bf16), gyr (f32)
__global__ __launch_bounds__(256) void loss_back4_k(
    const float* __restrict__ Kr, const float* __restrict__ Vr,
    const float* __restrict__ Y, const float* __restrict__ ln,
    const float* __restrict__ th, const float* __restrict__ wB,
    const float* __restrict__ wE,
    u16* __restrict__ dYb, u16* __restrict__ dYtW, u16* __restrict__ dYtE,
    float* __restrict__ gyr)
{
  __shared__ u16 lw[4][Dd];
  __shared__ u16 le[4][Dd];
  const int tid = threadIdx.x;
  const int w = tid >> 6, l = tid & 63;
  const int row = blockIdx.x * 4 + w;
  const int t = row & 63;
  const int d0 = l * 8;
  size_t base = (size_t)row * Dd + d0;

  float y[8], kk[8], vv[8], lv[8];
  *reinterpret_cast<float4*>(&y[0])  = *reinterpret_cast<const float4*>(Y + base);
  *reinterpret_cast<float4*>(&y[4])  = *reinterpret_cast<const float4*>(Y + base + 4);
  *reinterpret_cast<float4*>(&kk[0]) = *reinterpret_cast<const float4*>(Kr + base);
  *reinterpret_cast<float4*>(&kk[4]) = *reinterpret_cast<const float4*>(Kr + base + 4);
  *reinterpret_cast<float4*>(&vv[0]) = *reinterpret_cast<const float4*>(Vr + base);
  *reinterpret_cast<float4*>(&vv[4]) = *reinterpret_cast<const float4*>(Vr + base + 4);
  *reinterpret_cast<float4*>(&lv[0]) = *reinterpret_cast<const float4*>(ln + d0);
  *reinterpret_cast<float4*>(&lv[4]) = *reinterpret_cast<const float4*>(ln + d0 + 4);

  float ss = 0.f;
  #pragma unroll
  for (int j = 0; j < 8; ++j) ss += y[j] * y[j];
  ss = wave_sum(ss);
  float rr = rsqrtf(ss / (float)Dd + EPS);
  float c = 2.f * th[t] / (float)Dd;

  float g[8], s2 = 0.f;
  #pragma unroll
  for (int j = 0; j < 8; ++j) {
    g[j] = c * ((kk[j] + y[j] * rr * lv[j]) - vv[j]);
    s2 += g[j] * lv[j] * y[j];
  }
  s2 = wave_sum(s2);
  float coef = rr * rr * rr * s2 / (float)Dd;

  float wb = wB[row], we = wE[row];
  u16x8 pb;
  float gy[8];
  #pragma unroll
  for (int j = 0; j < 8; ++j) {
    float dv = rr * g[j] * lv[j] - coef * y[j];
    pb[j] = f2bf(dv);
    lw[w][d0 + j] = f2bf(dv * wb);
    le[w][d0 + j] = f2bf(dv * we);
    gy[j] = g[j] * y[j] * rr;
  }
  *reinterpret_cast<u16x8*>(dYb + base) = pb;
  *reinterpret_cast<float4*>(gyr + base)     = *reinterpret_cast<float4*>(&gy[0]);
  *reinterpret_cast<float4*>(gyr + base + 4) = *reinterpret_cast<float4*>(&gy[4]);

  __syncthreads();
  int r0 = blockIdx.x * 4;
  for (int d = tid; d < Dd; d += 256) {
    ushort4 pw, pe;
    pw.x = lw[0][d]; pw.y = lw[1][d]; pw.z = lw[2][d]; pw.w = lw[3][d];
    pe.x = le[0][d]; pe.y = le[1][d]; pe.z = le[2][d]; pe.w = le[3][d];
    *reinterpret_cast<ushort4*>(&dYtW[(size_t)d * RowsC + r0]) = pw;
    *reinterpret_cast<ushort4*>(&dYtE[(size_t)d * RowsC + r0]) = pe;
  }
}

// column-sum of gyr with both weightings + fused ln/Sln update
__global__ void colsum_upd_k(const float* __restrict__ gyr,
                             const float* __restrict__ wB, const float* __restrict__ wE,
                             float* __restrict__ lnc, float* __restrict__ Sln,
                             const float* __restrict__ scal) {
  int d = blockIdx.x * 256 + threadIdx.x;
  float sm = 0.f, se = 0.f;
  for (int r = 0; r < RowsC; ++r) {
    float v = gyr[(size_t)r * Dd + d];
    sm += wB[r] * v; se += wE[r] * v;
  }
  float p = lnc[d], s = Sln[d];
  lnc[d] = scal[0] * p + scal[1] * s - sm;
  Sln[d] = scal[2] * s - se;
}

// out[orig] = q + rms(y)*ln  (chunk-order rows -> original layout)
__global__ __launch_bounds__(256) void final_out_k(
    const float* __restrict__ Q, const float* __restrict__ Y,
    const float* __restrict__ ln, float* __restrict__ out) {
  __shared__ float red[256];
  int cr = blockIdx.x, tid = threadIdx.x;
  int ci = cr >> 8, wi = cr & 255, b = wi >> 6, t = wi & 63;
  size_t obase = ((size_t)b * Ss + ci * Cc + t) * Dd;
  size_t base = (size_t)cr * Dd;
  float y0 = Y[base + tid], y1 = Y[base + tid + 256];
  float ss = block_reduce_sum(y0 * y0 + y1 * y1, red);
  float r = rsqrtf(ss / (float)Dd + EPS);
  out[obase + tid]       = Q[base + tid]       + y0 * r * ln[tid];
  out[obase + tid + 256] = Q[base + tid + 256] + y1 * r * ln[tid + 256];
}

} // namespace

extern "C" void kernel_launch(void* const* d_in, const int* in_sizes, int n_in,
                              void* d_out, int out_size, void* d_ws, size_t ws_size,
                              hipStream_t stream)
{
  const float* x   = (const float*)d_in[0];
  const float* wq  = (const float*)d_in[1];
  const float* wkw = (const float*)d_in[2];
  const float* wvw = (const float*)d_in[3];
  const float* qn  = (const float*)d_in[4];
  const float* kn  = (const float*)d_in[5];
  const float* aw  = (const float*)d_in[6];
  const float* ab  = (const float*)d_in[7];
  const float* tw  = (const float*)d_in[8];
  const float* tb  = (const float*)d_in[9];
  const float* ew  = (const float*)d_in[10];
  const float* eb  = (const float*)d_in[11];
  const float* mw0 = (const float*)d_in[12];
  const float* mw1 = (const float*)d_in[13];
  const float* mln = (const float*)d_in[14];
  float* out = (float*)d_out;

  float* p = (float*)d_ws;
  auto alloc = [&](size_t n) { float* r = p; p += n; return r; };

  float* w0c  = alloc((size_t)Ii * Dd);
  float* Sw0  = alloc((size_t)Ii * Dd);
  float* w1c  = alloc((size_t)Dd * Ii);
  float* Sw1  = alloc((size_t)Dd * Ii);
  float* lnc  = alloc(Dd);
  float* Sln  = alloc(Dd);
  float* tmpK = alloc((size_t)RowsC * Dd);
  float* Krows= alloc((size_t)RowsC * Dd);
  float* Vrows= alloc((size_t)RowsC * Dd);
  float* Ybuf = alloc((size_t)RowsC * Dd);
  float* gyr  = alloc((size_t)RowsC * Dd);
  float* Z0   = alloc((size_t)RowsC * Ii);
  float* alv  = alloc(Ss);
  float* thv  = alloc(Ss);
  float* etv  = alloc(Ss);
  float* wBv  = alloc(nCk * RowsC);
  float* wEv  = alloc(nCk * RowsC);
  float* scal = alloc(nCk * 4);
  float* Qb   = alloc((size_t)RowsAll * Dd);
  float* Yr   = alloc((size_t)RowsAll * Dd);

  u16* q16 = (u16*)p;
  auto alloc16 = [&](size_t n) { u16* r = q16; q16 += n; return r; };
  u16* xcb_all = alloc16((size_t)RowsAll * Dd);   // chunk-ordered
  u16* wq_bf   = alloc16((size_t)Dd * Dd);
  u16* wkv_bf  = alloc16((size_t)Ii * Dd);        // [wk;wv] stacked
  u16* w0c_bf  = alloc16((size_t)Ii * Dd);
  u16* w1c_bf  = alloc16((size_t)Dd * Ii);
  u16* w1cT_bf = alloc16((size_t)Ii * Dd);
  u16* K_bf    = alloc16((size_t)RowsC * Dd);
  u16* KT      = alloc16((size_t)Dd * RowsC);
  u16* H_bf    = alloc16((size_t)RowsC * Ii);
  u16* Ht      = alloc16((size_t)Ii * RowsC);
  u16* dY_bf   = alloc16((size_t)RowsC * Dd);
  u16* dYtW    = alloc16((size_t)Dd * RowsC);
  u16* dYtE    = alloc16((size_t)Dd * RowsC);
  u16* dHtW    = alloc16((size_t)Ii * RowsC);
  u16* dHtE    = alloc16((size_t)Ii * RowsC);
  u16* Qb_bf   = alloc16((size_t)RowsAll * Dd);
  u16* Hr_bf   = alloc16((size_t)RowsAll * Ii);

  // ---- init
  hipMemcpyAsync(w0c, mw0, (size_t)Ii * Dd * 4, hipMemcpyDeviceToDevice, stream);
  hipMemcpyAsync(w1c, mw1, (size_t)Dd * Ii * 4, hipMemcpyDeviceToDevice, stream);
  hipMemcpyAsync(lnc, mln, (size_t)Dd * 4, hipMemcpyDeviceToDevice, stream);
  hipMemsetAsync(Sw0, 0, (size_t)Ii * Dd * 4, stream);
  hipMemsetAsync(Sw1, 0, (size_t)Dd * Ii * 4, stream);
  hipMemsetAsync(Sln, 0, (size_t)Dd * 4, stream);

  conv_k<<<(Dd * Dd) / 1024, 256, 0, stream>>>(wq, wq_bf, Dd * Dd);
  conv_k<<<(Dd * Dd) / 1024, 256, 0, stream>>>(wkw, wkv_bf, Dd * Dd);
  conv_k<<<(Dd * Dd) / 1024, 256, 0, stream>>>(wvw, wkv_bf + (size_t)Dd * Dd, Dd * Dd);
  conv_k<<<(Ii * Dd) / 1024, 256, 0, stream>>>(mw0, w0c_bf, Ii * Dd);
  conv_k<<<(Dd * Ii) / 1024, 256, 0, stream>>>(mw1, w1c_bf, Dd * Ii);
  transw_k<<<dim3(Ii / 64, Dd / 64), 256, 0, stream>>>(mw1, Dd, Ii, w1cT_bf);
  prep_k<<<Ss, 256, 0, stream>>>(x, aw, ab, tw, tb, ew, eb, xcb_all, alv, thv, etv);
  gate_scan_all_k<<<nCk, 64, 0, stream>>>(alv, etv, wBv, wEv, scal);

  for (int ci = 0; ci < nCk; ++ci) {
    const u16* xcb_c  = xcb_all + (size_t)ci * RowsC * Dd;
    const float* sc_c = scal + ci * 4;
    const float* wB_c = wBv + ci * RowsC;
    const float* wE_c = wEv + ci * RowsC;
    const float* th_c = thv + ci * Cc;

    // K/V projection (merged) -> tmpK (pre-norm), Vrows (silu'd)
    mgemm_k<64, 1><<<dim3(Ii / 64, RowsC / 64), 256, 0, stream>>>(
        xcb_c, wkv_bf, tmpK, Vrows, nullptr, nullptr, nullptr,
        nullptr, nullptr, nullptr, RowsC, Ii, Dd);
    silu_rms4_k<true><<<RowsC / 4, 256, 0, stream>>>(tmpK, Krows, K_bf, KT, kn);

    // forward MLP: Z0 (+H_bf, +Ht) then Y
    mgemm_k<64, 2><<<dim3(Ii / 64, RowsC / 64), 256, 0, stream>>>(
        K_bf, w0c_bf, Z0, nullptr, H_bf, Ht, nullptr,
        nullptr, nullptr, nullptr, RowsC, Ii, Dd);
    mgemm_k<64, 0><<<dim3(Dd / 64, RowsC / 64), 256, 0, stream>>>(
        H_bf, w1c_bf, Ybuf, nullptr, nullptr, nullptr, nullptr,
        nullptr, nullptr, nullptr, RowsC, Dd, Ii);

    // backward
    loss_back4_k<<<RowsC / 4, 256, 0, stream>>>(
        Krows, Vrows, Ybuf, lnc, th_c, wB_c, wE_c, dY_bf, dYtW, dYtE, gyr);
    colsum_upd_k<<<Dd / 256, 256, 0, stream>>>(gyr, wB_c, wE_c, lnc, Sln, sc_c);
    mgemm_k<64, 3><<<dim3(Ii / 64, RowsC / 64), 256, 0, stream>>>(
        dY_bf, w1cT_bf, nullptr, nullptr, nullptr, dHtW, dHtE,
        Z0, wB_c, wE_c, RowsC, Ii, Dd);

    // dual grad GEMMs with fused parameter update
    ggemm_k<true><<<dim3(Ii / 64, Dd / 64), 256, 0, stream>>>(
        dYtW, dYtE, Ht, w1c, Sw1, w1c_bf, w1cT_bf, sc_c, Dd, Ii, RowsC);
    ggemm_k<false><<<dim3(Dd / 64, Ii / 64), 256, 0, stream>>>(
        dHtW, dHtE, KT, w0c, Sw0, w0c_bf, nullptr, sc_c, Ii, Dd, RowsC);
  }

  // ---- retrieval (chunk-ordered rows throughout; final_out permutes back)
  mgemm_k<128, 0><<<dim3(Dd / 128, RowsAll / 128), 256, 0, stream>>>(
      xcb_all, wq_bf, Yr, nullptr, nullptr, nullptr, nullptr,
      nullptr, nullptr, nullptr, RowsAll, Dd, Dd);
  silu_rms4_k<false><<<RowsAll / 4, 256, 0, stream>>>(Yr, Qb, Qb_bf, nullptr, qn);
  mgemm_k<128, 4><<<dim3(Ii / 128, RowsAll / 128), 256, 0, stream>>>(
      Qb_bf, w0c_bf, nullptr, nullptr, Hr_bf, nullptr, nullptr,
      nullptr, nullptr, nullptr, RowsAll, Ii, Dd);
  mgemm_k<128, 0><<<dim3(Dd / 128, RowsAll / 128), 256, 0, stream>>>(
      Hr_bf, w1c_bf, Yr, nullptr, nullptr, nullptr, nullptr,
      nullptr, nullptr, nullptr, RowsAll, Dd, Ii);
  final_out_k<<<RowsAll, 256, 0, stream>>>(Qb, Yr, lnc, out);
}